// Round 1
// baseline (377.152 us; speedup 1.0000x reference)
//
#include <hip/hip_runtime.h>

// Workspace layout (float offsets)
#define WS_F     0      // f[128]
#define WS_FEAT0 128    // feat0[450]
#define WS_H1    640    // h1[450]
#define WS_FEAT  1152   // feat[450]
#define WS_H2    1664   // h2[450]

// K1: f[i] = sum_{t,p,c} x[4+t,p,c] * TwE[t,i] * PE[p,i] * CE[c,i]
// One block per i (128 blocks). Lanes split the contiguous c-dimension
// (float2 per lane), rows (t,p) iterate -> fully coalesced 512B wave loads.
__global__ __launch_bounds__(256) void k_f(
    const float* __restrict__ x, const float* __restrict__ TwE,
    const float* __restrict__ PE, const float* __restrict__ CE,
    float* __restrict__ f) {
  const int i = blockIdx.x;
  const int tid = threadIdx.x;
  __shared__ float sCE[128];
  __shared__ float sPE[256];
  __shared__ float sTw[4];
  __shared__ float coef[1024];
  __shared__ float red[4];
  if (tid < 128) sCE[tid] = CE[tid * 128 + i];
  sPE[tid] = PE[tid * 128 + i];
  if (tid < 4) sTw[tid] = TwE[tid * 128 + i];
  __syncthreads();
  // coef[q] = TwE[t,i]*PE[p,i], q = t*256 + p
#pragma unroll
  for (int k = 0; k < 4; ++k) {
    int q = tid + (k << 8);
    coef[q] = sTw[q >> 8] * sPE[q & 255];
  }
  __syncthreads();
  const int lane = tid & 63;
  const int wv = tid >> 6;
  const float2 ce = ((const float2*)sCE)[lane];  // this lane's fixed c-pair
  const float2* Xw = (const float2*)(x + 4 * 256 * 128);  // window start
  float acc = 0.f;
  const int q0 = wv * 256;  // each wave handles 256 of the 1024 (t,p) rows
#pragma unroll 8
  for (int k = 0; k < 256; ++k) {
    int q = q0 + k;
    float2 v = Xw[q * 64 + lane];  // coalesced: 64 lanes x 8B = 512B
    acc += coef[q] * (v.x * ce.x + v.y * ce.y);
  }
#pragma unroll
  for (int off = 32; off > 0; off >>= 1) acc += __shfl_down(acc, off);
  if (lane == 0) red[wv] = acc;
  __syncthreads();
  if (tid == 0) f[i] = red[0] + red[1] + red[2] + red[3];
}

// K2: feat0 = mE @ f  (450 rows, dot length 128). Wave per row.
__global__ __launch_bounds__(256) void k_mE(
    const float* __restrict__ mE, const float* __restrict__ f,
    float* __restrict__ feat0) {
  __shared__ float sf[128];
  const int tid = threadIdx.x;
  if (tid < 128) sf[tid] = f[tid];
  __syncthreads();
  const int lane = tid & 63;
  const int row = blockIdx.x * 4 + (tid >> 6);
  if (row >= 450) return;
  float2 v = ((const float2*)(mE + row * 128))[lane];
  float acc = v.x * sf[2 * lane] + v.y * sf[2 * lane + 1];
#pragma unroll
  for (int off = 32; off > 0; off >>= 1) acc += __shfl_down(acc, off);
  if (lane == 0) feat0[row] = acc;
}

// K3/K4/K5: vout = [relu](W @ vin + b), W is 450x450. Wave per row.
// Row byte stride 1800 is 8B-aligned -> float2 loads valid for every row.
__global__ __launch_bounds__(256) void k_mv450(
    const float* __restrict__ W, const float* __restrict__ b,
    const float* __restrict__ vin, float* __restrict__ vout, int relu) {
  __shared__ float sv[450];
  const int tid = threadIdx.x;
  if (tid < 450) sv[tid] = vin[tid];
  if (tid + 256 < 450) sv[tid + 256] = vin[tid + 256];
  __syncthreads();
  const int lane = tid & 63;
  const int row = blockIdx.x * 4 + (tid >> 6);
  if (row >= 450) return;
  const float2* Wr = (const float2*)(W + row * 450);  // 225 float2
  float acc = 0.f;
#pragma unroll
  for (int k = 0; k < 4; ++k) {
    int idx = lane + k * 64;
    if (idx < 225) {
      float2 w = Wr[idx];
      acc += w.x * sv[2 * idx] + w.y * sv[2 * idx + 1];
    }
  }
#pragma unroll
  for (int off = 32; off > 0; off >>= 1) acc += __shfl_down(acc, off);
  if (lane == 0) {
    float r = acc + b[row];
    if (relu) r = fmaxf(r, 0.f);
    vout[row] = r;
  }
}

// K6: out = dec_W2 @ h2 + dec_b2. 131072 rows x 450. Wave per row,
// 4 rows per 256-thread block, 32768 blocks. Pure HBM stream of 236 MB.
__global__ __launch_bounds__(256) void k_dec2(
    const float* __restrict__ W, const float* __restrict__ b,
    const float* __restrict__ h, float* __restrict__ out) {
  __shared__ float sv[450];
  const int tid = threadIdx.x;
  if (tid < 450) sv[tid] = h[tid];
  if (tid + 256 < 450) sv[tid + 256] = h[tid + 256];
  __syncthreads();
  const int lane = tid & 63;
  const int row = blockIdx.x * 4 + (tid >> 6);  // exactly 131072 rows
  const float2* Wr = (const float2*)(W + (size_t)row * 450);
  float acc = 0.f;
#pragma unroll
  for (int k = 0; k < 4; ++k) {
    int idx = lane + k * 64;
    if (idx < 225) {
      float2 w = Wr[idx];
      acc += w.x * sv[2 * idx] + w.y * sv[2 * idx + 1];
    }
  }
#pragma unroll
  for (int off = 32; off > 0; off >>= 1) acc += __shfl_down(acc, off);
  if (lane == 0) out[row] = acc + b[row];
}

extern "C" void kernel_launch(void* const* d_in, const int* in_sizes, int n_in,
                              void* d_out, int out_size, void* d_ws, size_t ws_size,
                              hipStream_t stream) {
  const float* x   = (const float*)d_in[0];
  // d_in[1] = t (int scalar) — unused: reference always takes x[-4:]
  const float* TwE = (const float*)d_in[2];
  const float* PE  = (const float*)d_in[3];
  const float* CE  = (const float*)d_in[4];
  const float* mE  = (const float*)d_in[5];
  const float* eW1 = (const float*)d_in[6];
  const float* eb1 = (const float*)d_in[7];
  const float* eW2 = (const float*)d_in[8];
  const float* eb2 = (const float*)d_in[9];
  const float* dW1 = (const float*)d_in[10];
  const float* db1 = (const float*)d_in[11];
  const float* dW2 = (const float*)d_in[12];
  const float* db2 = (const float*)d_in[13];
  float* out = (float*)d_out;
  float* ws  = (float*)d_ws;

  k_f    <<<128,   256, 0, stream>>>(x, TwE, PE, CE, ws + WS_F);
  k_mE   <<<113,   256, 0, stream>>>(mE, ws + WS_F, ws + WS_FEAT0);
  k_mv450<<<113,   256, 0, stream>>>(eW1, eb1, ws + WS_FEAT0, ws + WS_H1, 1);
  k_mv450<<<113,   256, 0, stream>>>(eW2, eb2, ws + WS_H1, ws + WS_FEAT, 0);
  k_mv450<<<113,   256, 0, stream>>>(dW1, db1, ws + WS_FEAT, ws + WS_H2, 1);
  k_dec2 <<<32768, 256, 0, stream>>>(dW2, db2, ws + WS_H2, out);
}